// Round 9
// baseline (805.328 us; speedup 1.0000x reference)
//
#include <hip/hip_runtime.h>
#include <stdint.h>
#include <math.h>

#define EPSV   1e-5f
#define BATCH  4096
#define GDIM   4096
#define NF0    384     // folded level-0 output features (64 terms * 6)
#define NSPLIT 8       // GEMM split-K factor

typedef __attribute__((ext_vector_type(8))) short bf16x8;
typedef __attribute__((ext_vector_type(4))) float f32x4;
typedef __attribute__((ext_vector_type(4))) uint32_t u32x4;

__device__ __forceinline__ uint32_t pkbf(float x, float y) {
    uint32_t a = __float_as_uint(x) + 0x8000u;
    uint32_t b = __float_as_uint(y) + 0x8000u;
    return __builtin_amdgcn_perm(b, a, 0x07060302u);
}
__device__ __forceinline__ uint16_t f2bf(float f) {
    return (uint16_t)((__float_as_uint(f) + 0x8000u) >> 16);
}
__device__ __forceinline__ float bf2f(uint16_t u) {
    union { uint32_t u; float f; } v; v.u = ((uint32_t)u) << 16; return v.f;
}
__device__ __forceinline__ void glds16(const uint16_t* g, short* l) {
    __builtin_amdgcn_global_load_lds(
        (const __attribute__((address_space(1))) void*)g,
        (__attribute__((address_space(3))) void*)l, 16, 0, 0);
}

// ---------------------------------------------------------------------------
// prep: blocks [0,8192): convert x f32->bf16 (8 elems/thread).
//       blocks [8192,9216): fold M0[t*6+h][g] = sum_i term_W[t,h,i]*gene_W[t,i,g]
//       block 0 also zeroes stats.
// ---------------------------------------------------------------------------
__global__ __launch_bounds__(256) void prep_kernel(
    const float* __restrict__ x, const float* __restrict__ gene_W,
    const float* __restrict__ term_W,
    uint16_t* __restrict__ xb, uint16_t* __restrict__ m0,
    float* __restrict__ stats)
{
    const int tid = threadIdx.x;
    if (blockIdx.x == 0)
        for (int j = tid; j < 1040; j += 256) stats[j] = 0.f;
    if (blockIdx.x < 8192) {
        size_t i = (size_t)blockIdx.x * 256 + tid;
        const float* src = x + i * 8;
        f32x4 v0 = *(const f32x4*)src;
        f32x4 v1 = *(const f32x4*)(src + 4);
        u32x4 p = (u32x4){pkbf(v0[0],v0[1]), pkbf(v0[2],v0[3]),
                          pkbf(v1[0],v1[1]), pkbf(v1[2],v1[3])};
        *(u32x4*)(xb + i * 8) = p;
    } else {
        __shared__ float Wl[144];
        const int bid = blockIdx.x - 8192;        // 0..1023
        const int t = bid >> 4;                   // term 0..63
        const int g = ((bid & 15) << 8) + tid;    // gene 0..4095
        if (tid < 144) Wl[tid] = term_W[t * 144 + tid];
        __syncthreads();
        float gw[24];
#pragma unroll
        for (int i = 0; i < 24; ++i)
            gw[i] = gene_W[((size_t)t * 24 + i) * GDIM + g];
#pragma unroll
        for (int h = 0; h < 6; ++h) {
            float s = 0.f;
#pragma unroll
            for (int i = 0; i < 24; ++i) s += Wl[h * 24 + i] * gw[i];
            m0[((size_t)(t * 6 + h)) * GDIM + g] = f2bf(s);
        }
    }
}

// ---------------------------------------------------------------------------
// m97-style GEMM: C[4096, 384] partials (bf16), split-K=8 over blockIdx.z.
// ---------------------------------------------------------------------------
__global__ __launch_bounds__(256) void gemm_glds(
    const uint16_t* __restrict__ A, const uint16_t* __restrict__ Bw,
    uint16_t* __restrict__ P, int KC)
{
    const int N = NF0, K = GDIM;
    __shared__ short sA[128 * 32];
    __shared__ short sB[128 * 32];
    const int tid  = threadIdx.x;
    const int m0   = blockIdx.y * 128, n0 = blockIdx.x * 128;
    const int kbase = blockIdx.z * KC;
    uint16_t* Cp = P + (size_t)blockIdx.z * ((size_t)BATCH * NF0);
    const int wave = tid >> 6, lane = tid & 63;
    const int wm   = (wave & 1) << 6, wn = (wave >> 1) << 6;
    const int lm   = lane & 15, quad = lane >> 4;

    f32x4 acc[4][4];
#pragma unroll
    for (int i = 0; i < 4; ++i)
#pragma unroll
        for (int j = 0; j < 4; ++j) acc[i][j] = (f32x4){0.f, 0.f, 0.f, 0.f};

    const int r0  = tid >> 2;
    const int c0e = (tid & 3) << 3;
    const uint16_t* gA = A  + (size_t)(m0 + r0) * K + kbase + c0e;
    const uint16_t* gB = Bw + (size_t)(n0 + r0) * K + kbase + c0e;
    short* la0 = &sA[tid * 8];
    short* la1 = &sA[2048 + tid * 8];
    short* lb0 = &sB[tid * 8];
    short* lb1 = &sB[2048 + tid * 8];
    const size_t rowskip = (size_t)64 * K;

    for (int k0 = 0; k0 < KC; k0 += 32) {
        __syncthreads();
        glds16(gA + k0,            la0);
        glds16(gA + rowskip + k0,  la1);
        glds16(gB + k0,            lb0);
        glds16(gB + rowskip + k0,  lb1);
        __syncthreads();
        bf16x8 af[4], bfr[4];
#pragma unroll
        for (int m = 0; m < 4; ++m)
            af[m]  = *(const bf16x8*)&sA[(wm + m * 16 + lm) * 32 + quad * 8];
#pragma unroll
        for (int n = 0; n < 4; ++n)
            bfr[n] = *(const bf16x8*)&sB[(wn + n * 16 + lm) * 32 + quad * 8];
#pragma unroll
        for (int m = 0; m < 4; ++m)
#pragma unroll
            for (int n = 0; n < 4; ++n)
                acc[m][n] = __builtin_amdgcn_mfma_f32_16x16x32_bf16(
                    af[m], bfr[n], acc[m][n], 0, 0, 0);
    }
#pragma unroll
    for (int n = 0; n < 4; ++n) {
        const int col = n0 + wn + n * 16 + lm;
#pragma unroll
        for (int m = 0; m < 4; ++m) {
            const int row = m0 + wm + m * 16 + (quad << 2);
            uint16_t* cp = Cp + (size_t)row * N + col;
#pragma unroll
            for (int r = 0; r < 4; ++r) cp[(size_t)r * N] = f2bf(acc[m][n][r]);
        }
    }
}

// ---------------------------------------------------------------------------
// lzero: z0 = tanh(sum_z P[z] + bias0); st0 per-feature sum/sumsq.
// ---------------------------------------------------------------------------
__global__ __launch_bounds__(384) void lzero_kernel(
    const uint16_t* __restrict__ P, const float* __restrict__ term_W,
    const float* __restrict__ term_b, const float* __restrict__ gene_b,
    float* __restrict__ z0, float* __restrict__ st0)
{
    const int f = threadIdx.x;            // 0..383
    const int t = f / 6, h = f - t * 6;
    const int rbase = blockIdx.x * 16;
    float bias = term_b[t * 6 + h];
#pragma unroll
    for (int i = 0; i < 24; ++i)
        bias += term_W[t * 144 + h * 24 + i] * gene_b[t * 24 + i];
    float s = 0.f, q = 0.f;
    for (int rl = 0; rl < 16; ++rl) {
        const size_t r = rbase + rl;
        float acc = bias;
#pragma unroll
        for (int z = 0; z < NSPLIT; ++z)
            acc += bf2f(P[(size_t)z * BATCH * NF0 + r * NF0 + f]);
        float zv = tanhf(acc);
        z0[r * NF0 + f] = zv;
        s += zv; q += zv * zv;
    }
    atomicAdd(&st0[f], s);
    atomicAdd(&st0[NF0 + f], q);
}

// ---------------------------------------------------------------------------
// L1: BN0(z0) -> aux cols 0..63, z1 = tanh(.), st1. (R4-proven level kernel.)
// ---------------------------------------------------------------------------
__global__ __launch_bounds__(256) void level1_kernel(
    const float* __restrict__ in, float* __restrict__ z_out,
    const float* __restrict__ stats_prev, float* __restrict__ stats_out,
    const float* __restrict__ term_W, const float* __restrict__ term_b,
    const float* __restrict__ bn_gamma, const float* __restrict__ bn_beta,
    const float* __restrict__ aux1_W, const float* __restrict__ aux1_b,
    const float* __restrict__ aux2_W, const float* __restrict__ aux2_b,
    float* __restrict__ out)
{
    constexpr int N = 16, ROWS = 16, OFF = 64, PREV_OFF = 0;
    constexpr int IN_W = 384, NFv = 96, NG = 16, ITERS = 1, NPREV = 64;

    __shared__ float Wl[144 * N];
    __shared__ float tbl[6 * N];
    __shared__ float aA[IN_W], aC[IN_W];
    __shared__ float a1wL[6 * NPREV];
    __shared__ float a1bL[NPREV], a2wL[NPREV], a2bL[NPREV];
    __shared__ float ps[NG * NFv], pq[NG * NFv];

    const int tid = threadIdx.x;
    for (int idx = tid; idx < 144 * N; idx += 256) {
        int t = idx / 144, fh = idx - t * 144;
        Wl[fh * N + t] = term_W[(OFF + t) * 144 + fh];
    }
    for (int idx = tid; idx < 6 * N; idx += 256) {
        int t = idx / 6, h = idx - t * 6;
        tbl[h * N + t] = term_b[(OFF + t) * 6 + h];
    }
    {
        const float invB = 1.0f / BATCH;
        for (int j = tid; j < IN_W; j += 256) {
            float s = stats_prev[j], q = stats_prev[IN_W + j];
            float mu = s * invB;
            float var = q * invB - mu * mu;
            float a = rsqrtf(var + EPSV) * bn_gamma[PREV_OFF * 6 + j];
            int t = j / 24, i = j - t * 24;
            aA[i * N + t] = a;
            aC[i * N + t] = bn_beta[PREV_OFF * 6 + j] - mu * a;
        }
        for (int idx = tid; idx < 6 * NPREV; idx += 256) {
            int t = idx / 6, h = idx - t * 6;
            a1wL[h * NPREV + t] = aux1_W[(PREV_OFF + t) * 6 + h];
        }
        for (int t = tid; t < NPREV; t += 256) {
            a1bL[t] = aux1_b[PREV_OFF + t];
            a2wL[t] = aux2_W[PREV_OFF + t];
            a2bL[t] = aux2_b[PREV_OFF + t];
        }
    }
    __syncthreads();

    const int term = tid & (N - 1);
    const int grp  = tid / N;
    const int r = blockIdx.x * ROWS + grp;
    const float* inrow = in + (size_t)r * IN_W + term * 24;
    float hv[24];
#pragma unroll
    for (int i4 = 0; i4 < 6; ++i4) {
        f32x4 v = *(const f32x4*)(inrow + 4 * i4);
        hv[4*i4+0] = v[0]; hv[4*i4+1] = v[1];
        hv[4*i4+2] = v[2]; hv[4*i4+3] = v[3];
    }
#pragma unroll
    for (int i = 0; i < 24; ++i)
        hv[i] = hv[i] * aA[i * N + term] + aC[i * N + term];
#pragma unroll
    for (int s = 0; s < 4; ++s) {
        const int tp = term * 4 + s;
        float acc = a1bL[tp];
#pragma unroll
        for (int h2 = 0; h2 < 6; ++h2) acc += hv[s * 6 + h2] * a1wL[h2 * NPREV + tp];
        out[(size_t)r * 86 + PREV_OFF + tp] = tanhf(acc) * a2wL[tp] + a2bL[tp];
    }
    float za[6];
#pragma unroll
    for (int h = 0; h < 6; ++h) za[h] = tbl[h * N + term];
#pragma unroll
    for (int i = 0; i < 24; ++i) {
        const float x = hv[i];
#pragma unroll
        for (int h = 0; h < 6; ++h) za[h] += x * Wl[(h * 24 + i) * N + term];
    }
    float* zr = z_out + (size_t)r * NFv + term * 6;
#pragma unroll
    for (int h = 0; h < 6; ++h) {
        float z = tanhf(za[h]);
        zr[h] = z;
        ps[grp * NFv + term * 6 + h] = z;
        pq[grp * NFv + term * 6 + h] = z * z;
    }
    __syncthreads();
    for (int f = tid; f < NFv; f += 256) {
        float s = 0.f, q = 0.f;
#pragma unroll
        for (int g2 = 0; g2 < NG; ++g2) { s += ps[g2 * NFv + f]; q += pq[g2 * NFv + f]; }
        atomicAdd(&stats_out[f], s);
        atomicAdd(&stats_out[NFv + f], q);
    }
}

// ---------------------------------------------------------------------------
// tail2: L2 + L3 + final in ONE block (1024 threads). __syncthreads is the
// batch-wide barrier; all stats via shuffle+LDS (no global atomics).
// z3/f live in LDS; z2 round-trips through a small global scratch.
// ---------------------------------------------------------------------------
__global__ __launch_bounds__(1024) void tail2_kernel(
    const float* __restrict__ z1, float* __restrict__ z2g,
    const float* __restrict__ st1,
    const float* __restrict__ term_W, const float* __restrict__ term_b,
    const float* __restrict__ bn_g, const float* __restrict__ bn_b,
    const float* __restrict__ a1W, const float* __restrict__ a1b,
    const float* __restrict__ a2W, const float* __restrict__ a2b,
    const float* __restrict__ fW, const float* __restrict__ fb,
    const float* __restrict__ fbn_g, const float* __restrict__ fbn_b,
    const float* __restrict__ fxW, const float* __restrict__ fxb,
    const float* __restrict__ foW, const float* __restrict__ fob,
    float* __restrict__ out)
{
    __shared__ float z3L[BATCH * 6];          // 98304 B; reused for f in phase C
    __shared__ float aA1[96], aC1[96];        // BN1 affine
    __shared__ float aA2[24], aC2[24];        // BN2 affine
    __shared__ float Wl2[4 * 144], Wl3[144];
    __shared__ float wred[16][48];
    __shared__ float stL[48];
    __shared__ float smix[64];                // small params: a3/c3, av/cv etc.

    const int tid = threadIdx.x;
    const int wv = tid >> 6, ln = tid & 63;
    const float invB = 1.0f / BATCH;

    // BN1 affine from st1 (global, written by L1's atomics)
    if (tid < 96) {
        float s = st1[tid], q = st1[96 + tid];
        float mu = s * invB, var = q * invB - mu * mu;
        float a = rsqrtf(var + EPSV) * bn_g[64 * 6 + tid];
        aA1[tid] = a;
        aC1[tid] = bn_b[64 * 6 + tid] - mu * a;
    }
    if (tid < 576) Wl2[tid] = term_W[80 * 144 + tid];
    else if (tid < 720) Wl3[tid - 576] = term_W[84 * 144 + (tid - 576)];
    __syncthreads();

    // ---------- Phase A: rows -> z2 (global scratch), st2 ----------
    float s24[24], q24[24];
#pragma unroll
    for (int j = 0; j < 24; ++j) { s24[j] = 0.f; q24[j] = 0.f; }
    for (int rp = 0; rp < 4; ++rp) {
        const int r = rp * 1024 + tid;
        const float* zr = z1 + (size_t)r * 96;
        float hv[96];
#pragma unroll
        for (int i4 = 0; i4 < 24; ++i4) {
            f32x4 v = *(const f32x4*)(zr + 4 * i4);
            hv[4*i4+0] = v[0]; hv[4*i4+1] = v[1];
            hv[4*i4+2] = v[2]; hv[4*i4+3] = v[3];
        }
#pragma unroll
        for (int i = 0; i < 96; ++i) hv[i] = hv[i] * aA1[i] + aC1[i];
        // aux cols 64..79 (level-1 heads)
#pragma unroll
        for (int tp = 0; tp < 16; ++tp) {
            float acc = a1b[64 + tp];
#pragma unroll
            for (int h = 0; h < 6; ++h) acc += hv[tp * 6 + h] * a1W[(64 + tp) * 6 + h];
            out[(size_t)r * 86 + 64 + tp] = tanhf(acc) * a2W[64 + tp] + a2b[64 + tp];
        }
        // z2 = tanh(hv . W2^T + b2), 4 terms x 6
        float* z2r = z2g + (size_t)r * 24;
#pragma unroll
        for (int t = 0; t < 4; ++t)
#pragma unroll
            for (int h = 0; h < 6; ++h) {
                float acc = term_b[(80 + t) * 6 + h];
#pragma unroll
                for (int i = 0; i < 24; ++i)
                    acc += hv[t * 24 + i] * Wl2[t * 144 + h * 24 + i];
                float z = tanhf(acc);
                z2r[t * 6 + h] = z;
                s24[t * 6 + h] += z;
                q24[t * 6 + h] += z * z;
            }
    }
#pragma unroll
    for (int off = 32; off >= 1; off >>= 1)
#pragma unroll
        for (int j = 0; j < 24; ++j) {
            s24[j] += __shfl_xor(s24[j], off, 64);
            q24[j] += __shfl_xor(q24[j], off, 64);
        }
    if (ln == 0)
#pragma unroll
        for (int j = 0; j < 24; ++j) { wred[wv][j] = s24[j]; wred[wv][24 + j] = q24[j]; }
    __syncthreads();
    if (tid < 48) {
        float s = 0.f;
#pragma unroll
        for (int w = 0; w < 16; ++w) s += wred[w][tid];
        stL[tid] = s;
    }
    __syncthreads();
    if (tid < 24) {
        float mu = stL[tid] * invB, var = stL[24 + tid] * invB - mu * mu;
        float a = rsqrtf(var + EPSV) * bn_g[80 * 6 + tid];
        aA2[tid] = a;
        aC2[tid] = bn_b[80 * 6 + tid] - mu * a;
    }
    __syncthreads();

    // ---------- Phase B: z2 -> aux 80..83, z3 (LDS), st3 ----------
    float s6[6], q6[6];
#pragma unroll
    for (int j = 0; j < 6; ++j) { s6[j] = 0.f; q6[j] = 0.f; }
    for (int rp = 0; rp < 4; ++rp) {
        const int r = rp * 1024 + tid;
        const float* z2r = z2g + (size_t)r * 24;
        float hv[24];
#pragma unroll
        for (int i4 = 0; i4 < 6; ++i4) {
            f32x4 v = *(const f32x4*)(z2r + 4 * i4);
            hv[4*i4+0] = v[0]; hv[4*i4+1] = v[1];
            hv[4*i4+2] = v[2]; hv[4*i4+3] = v[3];
        }
#pragma unroll
        for (int i = 0; i < 24; ++i) hv[i] = hv[i] * aA2[i] + aC2[i];
#pragma unroll
        for (int tp = 0; tp < 4; ++tp) {
            float acc = a1b[80 + tp];
#pragma unroll
            for (int h = 0; h < 6; ++h) acc += hv[tp * 6 + h] * a1W[(80 + tp) * 6 + h];
            out[(size_t)r * 86 + 80 + tp] = tanhf(acc) * a2W[80 + tp] + a2b[80 + tp];
        }
#pragma unroll
        for (int h = 0; h < 6; ++h) {
            float acc = term_b[84 * 6 + h];
#pragma unroll
            for (int i = 0; i < 24; ++i) acc += hv[i] * Wl3[h * 24 + i];
            float z = tanhf(acc);
            z3L[r * 6 + h] = z;
            s6[h] += z; q6[h] += z * z;
        }
    }
#pragma unroll
    for (int off = 32; off >= 1; off >>= 1)
#pragma unroll
        for (int j = 0; j < 6; ++j) {
            s6[j] += __shfl_xor(s6[j], off, 64);
            q6[j] += __shfl_xor(q6[j], off, 64);
        }
    if (ln == 0)
#pragma unroll
        for (int j = 0; j < 6; ++j) { wred[wv][j] = s6[j]; wred[wv][6 + j] = q6[j]; }
    __syncthreads();
    if (tid < 12) {
        float s = 0.f;
#pragma unroll
        for (int w = 0; w < 16; ++w) s += wred[w][tid];
        stL[tid] = s;
    }
    __syncthreads();
    if (tid < 6) {
        float mu = stL[tid] * invB, var = stL[6 + tid] * invB - mu * mu;
        float a = rsqrtf(var + EPSV) * bn_g[84 * 6 + tid];
        smix[tid] = a;                                  // a3
        smix[8 + tid] = bn_b[84 * 6 + tid] - mu * a;    // c3
    }
    __syncthreads();

    // ---------- Phase C: z3 -> aux 84, f (overwrite z3L), fstat ----------
    float fw[36], fbv[6];
#pragma unroll
    for (int j = 0; j < 36; ++j) fw[j] = fW[j];
#pragma unroll
    for (int j = 0; j < 6; ++j) fbv[j] = fb[j];
#pragma unroll
    for (int j = 0; j < 6; ++j) { s6[j] = 0.f; q6[j] = 0.f; }
    for (int rp = 0; rp < 4; ++rp) {
        const int r = rp * 1024 + tid;
        float h[6];
#pragma unroll
        for (int j = 0; j < 6; ++j) h[j] = z3L[r * 6 + j] * smix[j] + smix[8 + j];
        float acc = a1b[84];
#pragma unroll
        for (int j = 0; j < 6; ++j) acc += h[j] * a1W[84 * 6 + j];
        out[(size_t)r * 86 + 84] = tanhf(acc) * a2W[84] + a2b[84];
        float fv[6];
#pragma unroll
        for (int j = 0; j < 6; ++j) {
            float s = fbv[j];
#pragma unroll
            for (int k = 0; k < 6; ++k) s += h[k] * fw[j * 6 + k];
            fv[j] = tanhf(s);
            s6[j] += fv[j]; q6[j] += fv[j] * fv[j];
        }
        __syncthreads();   // everyone done reading z3L row slice before overwrite?  (same addresses per thread: safe w/o, kept for clarity)
#pragma unroll
        for (int j = 0; j < 6; ++j) z3L[r * 6 + j] = fv[j];
    }
#pragma unroll
    for (int off = 32; off >= 1; off >>= 1)
#pragma unroll
        for (int j = 0; j < 6; ++j) {
            s6[j] += __shfl_xor(s6[j], off, 64);
            q6[j] += __shfl_xor(q6[j], off, 64);
        }
    if (ln == 0)
#pragma unroll
        for (int j = 0; j < 6; ++j) { wred[wv][j] = s6[j]; wred[wv][6 + j] = q6[j]; }
    __syncthreads();
    if (tid < 12) {
        float s = 0.f;
#pragma unroll
        for (int w = 0; w < 16; ++w) s += wred[w][tid];
        stL[tid] = s;
    }
    __syncthreads();
    if (tid < 6) {
        float mu = stL[tid] * invB, var = stL[6 + tid] * invB - mu * mu;
        float a = rsqrtf(var + EPSV) * fbn_g[tid];
        smix[16 + tid] = a;                           // av
        smix[24 + tid] = fbn_b[tid] - mu * a;         // cv
    }
    __syncthreads();

    // ---------- Phase D: fbn + pred (col 85) ----------
    const float fxb0 = fxb[0], foW0 = foW[0], fob0 = fob[0];
    for (int rp = 0; rp < 4; ++rp) {
        const int r = rp * 1024 + tid;
        float acc = fxb0;
#pragma unroll
        for (int j = 0; j < 6; ++j)
            acc += (z3L[r * 6 + j] * smix[16 + j] + smix[24 + j]) * fxW[j];
        float pre = tanhf(acc) * foW0 + fob0;
        out[(size_t)r * 86 + 85] = 1.0f / (1.0f + expf(-pre));
    }
}

// ---------------------------------------------------------------------------
extern "C" void kernel_launch(void* const* d_in, const int* in_sizes, int n_in,
                              void* d_out, int out_size, void* d_ws, size_t ws_size,
                              hipStream_t stream)
{
    const float* x      = (const float*)d_in[0];
    const float* gene_W = (const float*)d_in[1];
    const float* gene_b = (const float*)d_in[2];
    const float* term_W = (const float*)d_in[3];
    const float* term_b = (const float*)d_in[4];
    const float* bn_g   = (const float*)d_in[5];
    const float* bn_b   = (const float*)d_in[6];
    const float* a1W    = (const float*)d_in[7];
    const float* a1b    = (const float*)d_in[8];
    const float* a2W    = (const float*)d_in[9];
    const float* a2b    = (const float*)d_in[10];
    const float* fW     = (const float*)d_in[11];
    const float* fb     = (const float*)d_in[12];
    const float* fbn_g  = (const float*)d_in[13];
    const float* fbn_b  = (const float*)d_in[14];
    const float* fxW    = (const float*)d_in[15];
    const float* fxb    = (const float*)d_in[16];
    const float* foW    = (const float*)d_in[17];
    const float* fob    = (const float*)d_in[18];
    float* out = (float*)d_out;

    const size_t XB  = 33554432;                          // x bf16
    const size_t M0B = (size_t)NF0 * GDIM * 2;            // 3,145,728
    const size_t PB  = (size_t)NSPLIT * BATCH * NF0 * 2;  // 25,165,824
    const size_t Z0B = (size_t)BATCH * NF0 * 4;           // 6,291,456
    const size_t Z1B = (size_t)BATCH * 96 * 4;            // 1,572,864
    const size_t Z2B = (size_t)BATCH * 24 * 4;            // 393,216

    char* ws = (char*)d_ws;
    uint16_t* xbuf = (uint16_t*)ws;
    uint16_t* m0b  = (uint16_t*)(ws + XB);
    uint16_t* pbuf = (uint16_t*)(ws + XB + M0B);
    float*    z0   = (float*)(ws + XB + M0B + PB);
    float*    z1   = (float*)(ws + XB + M0B + PB + Z0B);
    float*    z2g  = (float*)(ws + XB + M0B + PB + Z0B + Z1B);
    float*    stats = (float*)(ws + XB + M0B + PB + Z0B + Z1B + Z2B);
    float* st0 = stats;         // 384+384
    float* st1 = stats + 768;   // 96+96

    prep_kernel<<<9216, 256, 0, stream>>>(x, gene_W, term_W, xbuf, m0b, stats);
    gemm_glds<<<dim3(3, 32, NSPLIT), 256, 0, stream>>>(xbuf, m0b, pbuf, GDIM / NSPLIT);
    lzero_kernel<<<256, 384, 0, stream>>>(pbuf, term_W, term_b, gene_b, z0, st0);
    level1_kernel<<<256, 256, 0, stream>>>(
        z0, z1, st0, st1, term_W, term_b, bn_g, bn_b, a1W, a1b, a2W, a2b, out);
    tail2_kernel<<<1, 1024, 0, stream>>>(
        z1, z2g, st1, term_W, term_b, bn_g, bn_b, a1W, a1b, a2W, a2b,
        fW, fb, fbn_g, fbn_b, fxW, fxb, foW, fob, out);
}

// Round 10
// 356.154 us; speedup vs baseline: 2.2612x; 2.2612x over previous
//
#include <hip/hip_runtime.h>
#include <stdint.h>
#include <math.h>

#define EPSV   1e-5f
#define BATCH  4096
#define GDIM   4096
#define NF0    384     // folded level-0 output features (64 terms * 6)
#define NSPLIT 8       // GEMM split-K factor

typedef __attribute__((ext_vector_type(8))) short bf16x8;
typedef __attribute__((ext_vector_type(4))) float f32x4;
typedef __attribute__((ext_vector_type(4))) uint32_t u32x4;

__device__ __forceinline__ uint32_t pkbf(float x, float y) {
    uint32_t a = __float_as_uint(x) + 0x8000u;
    uint32_t b = __float_as_uint(y) + 0x8000u;
    return __builtin_amdgcn_perm(b, a, 0x07060302u);
}
__device__ __forceinline__ uint16_t f2bf(float f) {
    return (uint16_t)((__float_as_uint(f) + 0x8000u) >> 16);
}
__device__ __forceinline__ float bf2f(uint16_t u) {
    union { uint32_t u; float f; } v; v.u = ((uint32_t)u) << 16; return v.f;
}
__device__ __forceinline__ void glds16(const uint16_t* g, short* l) {
    __builtin_amdgcn_global_load_lds(
        (const __attribute__((address_space(1))) void*)g,
        (__attribute__((address_space(3))) void*)l, 16, 0, 0);
}

// ---------------------------------------------------------------------------
// prep: blocks [0,8192): convert x f32->bf16 (8 elems/thread).
//       blocks [8192,9216): fold M0[t*6+h][g] = sum_i term_W[t,h,i]*gene_W[t,i,g]
//       block 0 also zeroes stats.
// ---------------------------------------------------------------------------
__global__ __launch_bounds__(256) void prep_kernel(
    const float* __restrict__ x, const float* __restrict__ gene_W,
    const float* __restrict__ term_W,
    uint16_t* __restrict__ xb, uint16_t* __restrict__ m0,
    float* __restrict__ stats)
{
    const int tid = threadIdx.x;
    if (blockIdx.x == 0)
        for (int j = tid; j < 1040; j += 256) stats[j] = 0.f;
    if (blockIdx.x < 8192) {
        size_t i = (size_t)blockIdx.x * 256 + tid;
        const float* src = x + i * 8;
        f32x4 v0 = *(const f32x4*)src;
        f32x4 v1 = *(const f32x4*)(src + 4);
        u32x4 p = (u32x4){pkbf(v0[0],v0[1]), pkbf(v0[2],v0[3]),
                          pkbf(v1[0],v1[1]), pkbf(v1[2],v1[3])};
        *(u32x4*)(xb + i * 8) = p;
    } else {
        __shared__ float Wl[144];
        const int bid = blockIdx.x - 8192;        // 0..1023
        const int t = bid >> 4;                   // term 0..63
        const int g = ((bid & 15) << 8) + tid;    // gene 0..4095
        if (tid < 144) Wl[tid] = term_W[t * 144 + tid];
        __syncthreads();
        float gw[24];
#pragma unroll
        for (int i = 0; i < 24; ++i)
            gw[i] = gene_W[((size_t)t * 24 + i) * GDIM + g];
#pragma unroll
        for (int h = 0; h < 6; ++h) {
            float s = 0.f;
#pragma unroll
            for (int i = 0; i < 24; ++i) s += Wl[h * 24 + i] * gw[i];
            m0[((size_t)(t * 6 + h)) * GDIM + g] = f2bf(s);
        }
    }
}

// ---------------------------------------------------------------------------
// m97-style GEMM: C[4096, 384] partials (bf16), split-K=8 over blockIdx.z.
// ---------------------------------------------------------------------------
__global__ __launch_bounds__(256) void gemm_glds(
    const uint16_t* __restrict__ A, const uint16_t* __restrict__ Bw,
    uint16_t* __restrict__ P, int KC)
{
    const int N = NF0, K = GDIM;
    __shared__ short sA[128 * 32];
    __shared__ short sB[128 * 32];
    const int tid  = threadIdx.x;
    const int m0   = blockIdx.y * 128, n0 = blockIdx.x * 128;
    const int kbase = blockIdx.z * KC;
    uint16_t* Cp = P + (size_t)blockIdx.z * ((size_t)BATCH * NF0);
    const int wave = tid >> 6, lane = tid & 63;
    const int wm   = (wave & 1) << 6, wn = (wave >> 1) << 6;
    const int lm   = lane & 15, quad = lane >> 4;

    f32x4 acc[4][4];
#pragma unroll
    for (int i = 0; i < 4; ++i)
#pragma unroll
        for (int j = 0; j < 4; ++j) acc[i][j] = (f32x4){0.f, 0.f, 0.f, 0.f};

    const int r0  = tid >> 2;
    const int c0e = (tid & 3) << 3;
    const uint16_t* gA = A  + (size_t)(m0 + r0) * K + kbase + c0e;
    const uint16_t* gB = Bw + (size_t)(n0 + r0) * K + kbase + c0e;
    short* la0 = &sA[tid * 8];
    short* la1 = &sA[2048 + tid * 8];
    short* lb0 = &sB[tid * 8];
    short* lb1 = &sB[2048 + tid * 8];
    const size_t rowskip = (size_t)64 * K;

    for (int k0 = 0; k0 < KC; k0 += 32) {
        __syncthreads();
        glds16(gA + k0,            la0);
        glds16(gA + rowskip + k0,  la1);
        glds16(gB + k0,            lb0);
        glds16(gB + rowskip + k0,  lb1);
        __syncthreads();
        bf16x8 af[4], bfr[4];
#pragma unroll
        for (int m = 0; m < 4; ++m)
            af[m]  = *(const bf16x8*)&sA[(wm + m * 16 + lm) * 32 + quad * 8];
#pragma unroll
        for (int n = 0; n < 4; ++n)
            bfr[n] = *(const bf16x8*)&sB[(wn + n * 16 + lm) * 32 + quad * 8];
#pragma unroll
        for (int m = 0; m < 4; ++m)
#pragma unroll
            for (int n = 0; n < 4; ++n)
                acc[m][n] = __builtin_amdgcn_mfma_f32_16x16x32_bf16(
                    af[m], bfr[n], acc[m][n], 0, 0, 0);
    }
#pragma unroll
    for (int n = 0; n < 4; ++n) {
        const int col = n0 + wn + n * 16 + lm;
#pragma unroll
        for (int m = 0; m < 4; ++m) {
            const int row = m0 + wm + m * 16 + (quad << 2);
            uint16_t* cp = Cp + (size_t)row * N + col;
#pragma unroll
            for (int r = 0; r < 4; ++r) cp[(size_t)r * N] = f2bf(acc[m][n][r]);
        }
    }
}

// ---------------------------------------------------------------------------
// lzero: z0 = tanh(sum_z P[z] + bias0); st0 per-feature sum/sumsq.
// ---------------------------------------------------------------------------
__global__ __launch_bounds__(384) void lzero_kernel(
    const uint16_t* __restrict__ P, const float* __restrict__ term_W,
    const float* __restrict__ term_b, const float* __restrict__ gene_b,
    float* __restrict__ z0, float* __restrict__ st0)
{
    const int f = threadIdx.x;            // 0..383
    const int t = f / 6, h = f - t * 6;
    const int rbase = blockIdx.x * 16;
    float bias = term_b[t * 6 + h];
#pragma unroll
    for (int i = 0; i < 24; ++i)
        bias += term_W[t * 144 + h * 24 + i] * gene_b[t * 24 + i];
    float s = 0.f, q = 0.f;
    for (int rl = 0; rl < 16; ++rl) {
        const size_t r = rbase + rl;
        float acc = bias;
#pragma unroll
        for (int z = 0; z < NSPLIT; ++z)
            acc += bf2f(P[(size_t)z * BATCH * NF0 + r * NF0 + f]);
        float zv = tanhf(acc);
        z0[r * NF0 + f] = zv;
        s += zv; q += zv * zv;
    }
    atomicAdd(&st0[f], s);
    atomicAdd(&st0[NF0 + f], q);
}

// ---------------------------------------------------------------------------
// L1: BN0(z0) -> aux cols 0..63, z1 = tanh(.), st1. (R9-proven.)
// ---------------------------------------------------------------------------
__global__ __launch_bounds__(256) void level1_kernel(
    const float* __restrict__ in, float* __restrict__ z_out,
    const float* __restrict__ stats_prev, float* __restrict__ stats_out,
    const float* __restrict__ term_W, const float* __restrict__ term_b,
    const float* __restrict__ bn_gamma, const float* __restrict__ bn_beta,
    const float* __restrict__ aux1_W, const float* __restrict__ aux1_b,
    const float* __restrict__ aux2_W, const float* __restrict__ aux2_b,
    float* __restrict__ out)
{
    constexpr int N = 16, ROWS = 16, OFF = 64, PREV_OFF = 0;
    constexpr int IN_W = 384, NFv = 96, NG = 16, NPREV = 64;

    __shared__ float Wl[144 * N];
    __shared__ float tbl[6 * N];
    __shared__ float aA[IN_W], aC[IN_W];
    __shared__ float a1wL[6 * NPREV];
    __shared__ float a1bL[NPREV], a2wL[NPREV], a2bL[NPREV];
    __shared__ float ps[NG * NFv], pq[NG * NFv];

    const int tid = threadIdx.x;
    for (int idx = tid; idx < 144 * N; idx += 256) {
        int t = idx / 144, fh = idx - t * 144;
        Wl[fh * N + t] = term_W[(OFF + t) * 144 + fh];
    }
    for (int idx = tid; idx < 6 * N; idx += 256) {
        int t = idx / 6, h = idx - t * 6;
        tbl[h * N + t] = term_b[(OFF + t) * 6 + h];
    }
    {
        const float invB = 1.0f / BATCH;
        for (int j = tid; j < IN_W; j += 256) {
            float s = stats_prev[j], q = stats_prev[IN_W + j];
            float mu = s * invB;
            float var = q * invB - mu * mu;
            float a = rsqrtf(var + EPSV) * bn_gamma[PREV_OFF * 6 + j];
            int t = j / 24, i = j - t * 24;
            aA[i * N + t] = a;
            aC[i * N + t] = bn_beta[PREV_OFF * 6 + j] - mu * a;
        }
        for (int idx = tid; idx < 6 * NPREV; idx += 256) {
            int t = idx / 6, h = idx - t * 6;
            a1wL[h * NPREV + t] = aux1_W[(PREV_OFF + t) * 6 + h];
        }
        for (int t = tid; t < NPREV; t += 256) {
            a1bL[t] = aux1_b[PREV_OFF + t];
            a2wL[t] = aux2_W[PREV_OFF + t];
            a2bL[t] = aux2_b[PREV_OFF + t];
        }
    }
    __syncthreads();

    const int term = tid & (N - 1);
    const int grp  = tid / N;
    const int r = blockIdx.x * ROWS + grp;
    const float* inrow = in + (size_t)r * IN_W + term * 24;
    float hv[24];
#pragma unroll
    for (int i4 = 0; i4 < 6; ++i4) {
        f32x4 v = *(const f32x4*)(inrow + 4 * i4);
        hv[4*i4+0] = v[0]; hv[4*i4+1] = v[1];
        hv[4*i4+2] = v[2]; hv[4*i4+3] = v[3];
    }
#pragma unroll
    for (int i = 0; i < 24; ++i)
        hv[i] = hv[i] * aA[i * N + term] + aC[i * N + term];
#pragma unroll
    for (int s = 0; s < 4; ++s) {
        const int tp = term * 4 + s;
        float acc = a1bL[tp];
#pragma unroll
        for (int h2 = 0; h2 < 6; ++h2) acc += hv[s * 6 + h2] * a1wL[h2 * NPREV + tp];
        out[(size_t)r * 86 + PREV_OFF + tp] = tanhf(acc) * a2wL[tp] + a2bL[tp];
    }
    float za[6];
#pragma unroll
    for (int h = 0; h < 6; ++h) za[h] = tbl[h * N + term];
#pragma unroll
    for (int i = 0; i < 24; ++i) {
        const float x = hv[i];
#pragma unroll
        for (int h = 0; h < 6; ++h) za[h] += x * Wl[(h * 24 + i) * N + term];
    }
    float* zr = z_out + (size_t)r * NFv + term * 6;
#pragma unroll
    for (int h = 0; h < 6; ++h) {
        float z = tanhf(za[h]);
        zr[h] = z;
        ps[grp * NFv + term * 6 + h] = z;
        pq[grp * NFv + term * 6 + h] = z * z;
    }
    __syncthreads();
    for (int f = tid; f < NFv; f += 256) {
        float s = 0.f, q = 0.f;
#pragma unroll
        for (int g2 = 0; g2 < NG; ++g2) { s += ps[g2 * NFv + f]; q += pq[g2 * NFv + f]; }
        atomicAdd(&stats_out[f], s);
        atomicAdd(&stats_out[NFv + f], q);
    }
}

// ---------------------------------------------------------------------------
// L2 (R8-proven level kernel, instantiated N=4): BN1(z1) -> aux 64..79,
// z2 = tanh(.), st2. 64 blocks x 256.
// ---------------------------------------------------------------------------
__global__ __launch_bounds__(256) void level2_kernel(
    const float* __restrict__ in, float* __restrict__ z_out,
    const float* __restrict__ stats_prev, float* __restrict__ stats_out,
    const float* __restrict__ term_W, const float* __restrict__ term_b,
    const float* __restrict__ bn_gamma, const float* __restrict__ bn_beta,
    const float* __restrict__ aux1_W, const float* __restrict__ aux1_b,
    const float* __restrict__ aux2_W, const float* __restrict__ aux2_b,
    float* __restrict__ out)
{
    constexpr int N = 4, ROWS = 64, OFF = 80, PREV_OFF = 64;
    constexpr int IN_W = 96, NFv = 24, NG = 64, NPREV = 16;

    __shared__ float Wl[144 * N];
    __shared__ float tbl[6 * N];
    __shared__ float aA[IN_W], aC[IN_W];
    __shared__ float a1wL[6 * NPREV];
    __shared__ float a1bL[NPREV], a2wL[NPREV], a2bL[NPREV];
    __shared__ float ps[NG * NFv], pq[NG * NFv];

    const int tid = threadIdx.x;
    for (int idx = tid; idx < 144 * N; idx += 256) {
        int t = idx / 144, fh = idx - t * 144;
        Wl[fh * N + t] = term_W[(OFF + t) * 144 + fh];
    }
    if (tid < 24) { int t = tid / 6, h = tid - t * 6; tbl[h * N + t] = term_b[(OFF + t) * 6 + h]; }
    {
        const float invB = 1.0f / BATCH;
        for (int j = tid; j < IN_W; j += 256) {
            float s = stats_prev[j], q = stats_prev[IN_W + j];
            float mu = s * invB;
            float var = q * invB - mu * mu;
            float a = rsqrtf(var + EPSV) * bn_gamma[PREV_OFF * 6 + j];
            int t = j / 24, i = j - t * 24;
            aA[i * N + t] = a;
            aC[i * N + t] = bn_beta[PREV_OFF * 6 + j] - mu * a;
        }
        for (int idx = tid; idx < 6 * NPREV; idx += 256) {
            int t = idx / 6, h = idx - t * 6;
            a1wL[h * NPREV + t] = aux1_W[(PREV_OFF + t) * 6 + h];
        }
        for (int t = tid; t < NPREV; t += 256) {
            a1bL[t] = aux1_b[PREV_OFF + t];
            a2wL[t] = aux2_W[PREV_OFF + t];
            a2bL[t] = aux2_b[PREV_OFF + t];
        }
    }
    __syncthreads();

    const int term = tid & (N - 1);
    const int grp  = tid / N;
    const int r = blockIdx.x * ROWS + grp;
    const float* inrow = in + (size_t)r * IN_W + term * 24;
    float hv[24];
#pragma unroll
    for (int i4 = 0; i4 < 6; ++i4) {
        f32x4 v = *(const f32x4*)(inrow + 4 * i4);
        hv[4*i4+0] = v[0]; hv[4*i4+1] = v[1];
        hv[4*i4+2] = v[2]; hv[4*i4+3] = v[3];
    }
#pragma unroll
    for (int i = 0; i < 24; ++i)
        hv[i] = hv[i] * aA[i * N + term] + aC[i * N + term];
#pragma unroll
    for (int s = 0; s < 4; ++s) {
        const int tp = term * 4 + s;
        float acc = a1bL[tp];
#pragma unroll
        for (int h2 = 0; h2 < 6; ++h2) acc += hv[s * 6 + h2] * a1wL[h2 * NPREV + tp];
        out[(size_t)r * 86 + PREV_OFF + tp] = tanhf(acc) * a2wL[tp] + a2bL[tp];
    }
    float za[6];
#pragma unroll
    for (int h = 0; h < 6; ++h) za[h] = tbl[h * N + term];
#pragma unroll
    for (int i = 0; i < 24; ++i) {
        const float x = hv[i];
#pragma unroll
        for (int h = 0; h < 6; ++h) za[h] += x * Wl[(h * 24 + i) * N + term];
    }
    float* zr = z_out + (size_t)r * NFv + term * 6;
#pragma unroll
    for (int h = 0; h < 6; ++h) {
        float z = tanhf(za[h]);
        zr[h] = z;
        ps[grp * NFv + term * 6 + h] = z;
        pq[grp * NFv + term * 6 + h] = z * z;
    }
    __syncthreads();
    for (int f = tid; f < NFv; f += 256) {
        float s = 0.f, q = 0.f;
#pragma unroll
        for (int g2 = 0; g2 < NG; ++g2) { s += ps[g2 * NFv + f]; q += pq[g2 * NFv + f]; }
        atomicAdd(&stats_out[f], s);
        atomicAdd(&stats_out[NFv + f], q);
    }
}

// ---------------------------------------------------------------------------
// tail3: L3 + final in ONE block (1024 threads, 4 rows/thread), register-light:
// per row only hv[24] chunk live; z3 (then f) carried as 24 regs/thread.
// Stats via shuffle + LDS. No global atomics.
// ---------------------------------------------------------------------------
__global__ __launch_bounds__(1024) void tail3_kernel(
    const float* __restrict__ z2g, const float* __restrict__ st2,
    const float* __restrict__ term_W, const float* __restrict__ term_b,
    const float* __restrict__ bn_g, const float* __restrict__ bn_b,
    const float* __restrict__ a1W, const float* __restrict__ a1b,
    const float* __restrict__ a2W, const float* __restrict__ a2b,
    const float* __restrict__ fW, const float* __restrict__ fb,
    const float* __restrict__ fbn_g, const float* __restrict__ fbn_b,
    const float* __restrict__ fxW, const float* __restrict__ fxb,
    const float* __restrict__ foW, const float* __restrict__ fob,
    float* __restrict__ out)
{
    __shared__ float aA2[24], aC2[24];
    __shared__ float Wl3[144], fwL[36], fbL[6];
    __shared__ float a1wL[30], a1bL[5], a2wL[5], a2bL[5];   // terms 80..84
    __shared__ float wred[16][12], stL[12], smix[32];
    const int tid = threadIdx.x;
    const int wv = tid >> 6, ln = tid & 63;
    const float invB = 1.0f / BATCH;

    if (tid < 24) {
        float s = st2[tid], q = st2[24 + tid];
        float mu = s * invB, var = q * invB - mu * mu;
        float a = rsqrtf(var + EPSV) * bn_g[80 * 6 + tid];
        aA2[tid] = a;
        aC2[tid] = bn_b[80 * 6 + tid] - mu * a;
    }
    if (tid >= 64 && tid < 208) Wl3[tid - 64] = term_W[84 * 144 + (tid - 64)];
    if (tid >= 256 && tid < 292) fwL[tid - 256] = fW[tid - 256];
    if (tid >= 292 && tid < 298) fbL[tid - 292] = fb[tid - 292];
    if (tid >= 320 && tid < 350) a1wL[tid - 320] = a1W[80 * 6 + (tid - 320)];
    if (tid >= 352 && tid < 357) {
        a1bL[tid - 352] = a1b[80 + (tid - 352)];
        a2wL[tid - 352] = a2W[80 + (tid - 352)];
        a2bL[tid - 352] = a2b[80 + (tid - 352)];
    }
    __syncthreads();

    // ---------- L3: z2 -> aux 80..83, z3 (regs), st3 ----------
    float z3r[4][6];
    float s6[6], q6[6];
#pragma unroll
    for (int j = 0; j < 6; ++j) { s6[j] = 0.f; q6[j] = 0.f; }
    for (int rp = 0; rp < 4; ++rp) {
        const int r = rp * 1024 + tid;
        const float* z2r = z2g + (size_t)r * 24;
        float hv[24];
#pragma unroll
        for (int i4 = 0; i4 < 6; ++i4) {
            f32x4 v = *(const f32x4*)(z2r + 4 * i4);
            hv[4*i4+0] = v[0]; hv[4*i4+1] = v[1];
            hv[4*i4+2] = v[2]; hv[4*i4+3] = v[3];
        }
#pragma unroll
        for (int i = 0; i < 24; ++i) hv[i] = hv[i] * aA2[i] + aC2[i];
#pragma unroll
        for (int tp = 0; tp < 4; ++tp) {
            float acc = a1bL[tp];
#pragma unroll
            for (int h = 0; h < 6; ++h) acc += hv[tp * 6 + h] * a1wL[tp * 6 + h];
            out[(size_t)r * 86 + 80 + tp] = tanhf(acc) * a2wL[tp] + a2bL[tp];
        }
#pragma unroll
        for (int h = 0; h < 6; ++h) {
            float acc = term_b[84 * 6 + h];
#pragma unroll
            for (int i = 0; i < 24; ++i) acc += hv[i] * Wl3[h * 24 + i];
            float z = tanhf(acc);
            z3r[rp][h] = z;
            s6[h] += z; q6[h] += z * z;
        }
    }
#pragma unroll
    for (int off = 32; off >= 1; off >>= 1)
#pragma unroll
        for (int j = 0; j < 6; ++j) {
            s6[j] += __shfl_xor(s6[j], off, 64);
            q6[j] += __shfl_xor(q6[j], off, 64);
        }
    if (ln == 0)
#pragma unroll
        for (int j = 0; j < 6; ++j) { wred[wv][j] = s6[j]; wred[wv][6 + j] = q6[j]; }
    __syncthreads();
    if (tid < 12) {
        float s = 0.f;
#pragma unroll
        for (int w = 0; w < 16; ++w) s += wred[w][tid];
        stL[tid] = s;
    }
    __syncthreads();
    if (tid < 6) {
        float mu = stL[tid] * invB, var = stL[6 + tid] * invB - mu * mu;
        float a = rsqrtf(var + EPSV) * bn_g[84 * 6 + tid];
        smix[tid] = a;                                  // a3
        smix[8 + tid] = bn_b[84 * 6 + tid] - mu * a;    // c3
    }
    __syncthreads();

    // ---------- final pass 1: aux84, f (overwrite z3r), fstat ----------
#pragma unroll
    for (int j = 0; j < 6; ++j) { s6[j] = 0.f; q6[j] = 0.f; }
    for (int rp = 0; rp < 4; ++rp) {
        const int r = rp * 1024 + tid;
        float h[6];
#pragma unroll
        for (int j = 0; j < 6; ++j) h[j] = z3r[rp][j] * smix[j] + smix[8 + j];
        float acc = a1bL[4];
#pragma unroll
        for (int j = 0; j < 6; ++j) acc += h[j] * a1wL[24 + j];
        out[(size_t)r * 86 + 84] = tanhf(acc) * a2wL[4] + a2bL[4];
#pragma unroll
        for (int j = 0; j < 6; ++j) {
            float s = fbL[j];
#pragma unroll
            for (int k = 0; k < 6; ++k) s += h[k] * fwL[j * 6 + k];
            float fv = tanhf(s);
            z3r[rp][j] = fv;
            s6[j] += fv; q6[j] += fv * fv;
        }
    }
#pragma unroll
    for (int off = 32; off >= 1; off >>= 1)
#pragma unroll
        for (int j = 0; j < 6; ++j) {
            s6[j] += __shfl_xor(s6[j], off, 64);
            q6[j] += __shfl_xor(q6[j], off, 64);
        }
    if (ln == 0)
#pragma unroll
        for (int j = 0; j < 6; ++j) { wred[wv][j] = s6[j]; wred[wv][6 + j] = q6[j]; }
    __syncthreads();
    if (tid < 12) {
        float s = 0.f;
#pragma unroll
        for (int w = 0; w < 16; ++w) s += wred[w][tid];
        stL[tid] = s;
    }
    __syncthreads();
    if (tid < 6) {
        float mu = stL[tid] * invB, var = stL[6 + tid] * invB - mu * mu;
        float a = rsqrtf(var + EPSV) * fbn_g[tid];
        smix[16 + tid] = a;                           // av
        smix[24 + tid] = fbn_b[tid] - mu * a;         // cv
    }
    __syncthreads();

    // ---------- final pass 2: fbn + pred (col 85) ----------
    const float fxb0 = fxb[0], foW0 = foW[0], fob0 = fob[0];
    for (int rp = 0; rp < 4; ++rp) {
        const int r = rp * 1024 + tid;
        float acc = fxb0;
#pragma unroll
        for (int j = 0; j < 6; ++j)
            acc += (z3r[rp][j] * smix[16 + j] + smix[24 + j]) * fxW[j];
        float pre = tanhf(acc) * foW0 + fob0;
        out[(size_t)r * 86 + 85] = 1.0f / (1.0f + expf(-pre));
    }
}

// ---------------------------------------------------------------------------
extern "C" void kernel_launch(void* const* d_in, const int* in_sizes, int n_in,
                              void* d_out, int out_size, void* d_ws, size_t ws_size,
                              hipStream_t stream)
{
    const float* x      = (const float*)d_in[0];
    const float* gene_W = (const float*)d_in[1];
    const float* gene_b = (const float*)d_in[2];
    const float* term_W = (const float*)d_in[3];
    const float* term_b = (const float*)d_in[4];
    const float* bn_g   = (const float*)d_in[5];
    const float* bn_b   = (const float*)d_in[6];
    const float* a1W    = (const float*)d_in[7];
    const float* a1b    = (const float*)d_in[8];
    const float* a2W    = (const float*)d_in[9];
    const float* a2b    = (const float*)d_in[10];
    const float* fW     = (const float*)d_in[11];
    const float* fb     = (const float*)d_in[12];
    const float* fbn_g  = (const float*)d_in[13];
    const float* fbn_b  = (const float*)d_in[14];
    const float* fxW    = (const float*)d_in[15];
    const float* fxb    = (const float*)d_in[16];
    const float* foW    = (const float*)d_in[17];
    const float* fob    = (const float*)d_in[18];
    float* out = (float*)d_out;

    const size_t XB  = 33554432;                          // x bf16
    const size_t M0B = (size_t)NF0 * GDIM * 2;            // 3,145,728
    const size_t PB  = (size_t)NSPLIT * BATCH * NF0 * 2;  // 25,165,824
    const size_t Z0B = (size_t)BATCH * NF0 * 4;           // 6,291,456
    const size_t Z1B = (size_t)BATCH * 96 * 4;            // 1,572,864
    const size_t Z2B = (size_t)BATCH * 24 * 4;            // 393,216

    char* ws = (char*)d_ws;
    uint16_t* xbuf = (uint16_t*)ws;
    uint16_t* m0b  = (uint16_t*)(ws + XB);
    uint16_t* pbuf = (uint16_t*)(ws + XB + M0B);
    float*    z0   = (float*)(ws + XB + M0B + PB);
    float*    z1   = (float*)(ws + XB + M0B + PB + Z0B);
    float*    z2g  = (float*)(ws + XB + M0B + PB + Z0B + Z1B);
    float*    stats = (float*)(ws + XB + M0B + PB + Z0B + Z1B + Z2B);
    float* st0 = stats;         // 384+384
    float* st1 = stats + 768;   // 96+96
    float* st2 = stats + 960;   // 24+24

    prep_kernel<<<9216, 256, 0, stream>>>(x, gene_W, term_W, xbuf, m0b, stats);
    gemm_glds<<<dim3(3, 32, NSPLIT), 256, 0, stream>>>(xbuf, m0b, pbuf, GDIM / NSPLIT);
    lzero_kernel<<<256, 384, 0, stream>>>(pbuf, term_W, term_b, gene_b, z0, st0);
    level1_kernel<<<256, 256, 0, stream>>>(
        z0, z1, st0, st1, term_W, term_b, bn_g, bn_b, a1W, a1b, a2W, a2b, out);
    level2_kernel<<<64, 256, 0, stream>>>(
        z1, z2g, st1, st2, term_W, term_b, bn_g, bn_b, a1W, a1b, a2W, a2b, out);
    tail3_kernel<<<1, 1024, 0, stream>>>(
        z2g, st2, term_W, term_b, bn_g, bn_b, a1W, a1b, a2W, a2b,
        fW, fb, fbn_g, fbn_b, fxW, fxb, foW, fob, out);
}